// Round 5
// baseline (143.840 us; speedup 1.0000x reference)
//
#include <hip/hip_runtime.h>
#include <hip/hip_bf16.h>
#include <stdint.h>

#define FH 45
#define FW 80
#define CIN 64
#define CF 64
#define NANCH 2784
#define BB 16
#define JP 80            // padded j dimension (75 real: 2 cls + 73 reg)
#define JN 75
#define MROW (FH * FW)         // 3600 rows per batch
#define SB ((MROW + 1) * JP)   // per-batch M stride in ELEMENTS, +1 dummy zero row
#define ZOFF (MROW * JP)       // element offset of the zero row within a batch
#define ANB 25                 // anchors per k3 block
#define CPB ((NANCH + ANB - 1) / ANB)   // 112 chunks per batch
#define SLAB_BYTES (SB * 2)    // 576160 bytes per batch slab (bf16)
#define PFQ 5376               // prefetch quota per block (112*5376 >= SLAB_BYTES)

static __device__ __forceinline__ uint32_t pkbf(float a, float b) {
    uint32_t lo = (uint32_t)__bfloat16_as_ushort(__float2bfloat16(a));
    uint32_t hi = (uint32_t)__bfloat16_as_ushort(__float2bfloat16(b));
    return lo | (hi << 16);
}

// ---------------- k1: V[y][ci][j] (f32), biasM[y][j], offset table ----------------
__global__ __launch_bounds__(256) void k1_weights(
    const float* __restrict__ conv_w, const float* __restrict__ conv_b,
    const float* __restrict__ cls_w, const float* __restrict__ reg_w,
    const int* __restrict__ cut_xs, const uint8_t* __restrict__ invalid,
    float* __restrict__ V, float* __restrict__ biasM, int* __restrict__ off) {
    int blk = blockIdx.x;
    int tid = threadIdx.x;
    if (blk >= 90) {
        int idx = (blk - 90) * 256 + tid;
        if (idx < NANCH * FH) {
            int y = idx % FH;
            off[idx] = invalid[idx] ? ZOFF : (y * FW + cut_xs[idx]) * JP;
        }
        return;
    }
    int y = blk >> 1;
    int j0 = (blk & 1) * 40;
    __shared__ float cw[CF * CIN];   // 16 KB
    __shared__ float wl[CF * 40];    // 10 KB
    __shared__ float cb[CF];
    for (int i = tid; i < CF * CIN; i += 256) cw[i] = conv_w[i];
    if (tid < CF) cb[tid] = conv_b[tid];
    for (int i = tid; i < CF * 40; i += 256) {
        int c = i / 40, jl = i % 40, j = j0 + jl;
        float v = 0.f;
        if (j < 2) v = cls_w[(c * FH + y) * 2 + j];
        else if (j < JN) v = reg_w[(c * FH + y) * 73 + (j - 2)];
        wl[i] = v;
    }
    __syncthreads();
    int ci = tid & 63;
    int jb = tid >> 6;               // 0..3
    float acc[10];
    #pragma unroll
    for (int k = 0; k < 10; ++k) acc[k] = 0.f;
    for (int c = 0; c < CF; ++c) {
        float a = cw[c * CIN + ci];
        #pragma unroll
        for (int k = 0; k < 10; ++k)
            acc[k] = fmaf(a, wl[c * 40 + jb + 4 * k], acc[k]);
    }
    #pragma unroll
    for (int k = 0; k < 10; ++k)
        V[y * (CIN * JP) + ci * JP + j0 + jb + 4 * k] = acc[k];
    if (tid < 40) {
        float s = 0.f;
        for (int c = 0; c < CF; ++c) s += cb[c] * wl[c * 40 + tid];
        biasM[y * JP + j0 + tid] = s;
    }
}

// ---------------- k2: M[b][(y*FW+x)][j] (bf16) = sum_ci x*V + biasM ----------------
// XCD-swizzled by b so slab b's lines are written (and cached) on XCD(b%..).
__global__ __launch_bounds__(256) void k2_feat(
    const float* __restrict__ x, const float* __restrict__ V,
    const float* __restrict__ biasM, __hip_bfloat16* __restrict__ M) {
    int wg = blockIdx.x;
    int b = (wg % 8) * 2 + ((wg >> 3) & 1);
    int y = wg >> 4;                 // 0..44
    __shared__ float xl[CIN * FW];   // 20 KB
    __shared__ float vl[CIN * JP];   // 20 KB
    __shared__ float bl[JP];
    int tid = threadIdx.x;
    for (int t = tid; t < CIN * FW; t += 256) {
        int ci = t / FW, xc = t % FW;
        xl[t] = x[((b * CIN + ci) * FH + y) * FW + xc];
    }
    const float* vsrc = V + y * (CIN * JP);
    for (int t = tid; t < CIN * JP; t += 256) vl[t] = vsrc[t];
    if (tid < JP) bl[tid] = biasM[y * JP + tid];
    __hip_bfloat16* Mb = M + (size_t)b * SB;
    if (y == 0 && tid < JP) Mb[ZOFF + tid] = __float2bfloat16(0.f);  // dummy zero row
    __syncthreads();
    if (tid < 200) {                  // 20 x-groups(4) x 10 j-groups(8)
        int tx = tid % 20;
        int tj = tid / 20;
        int x0 = tx * 4, jg0 = tj * 8;
        float acc[4][8];
        for (int xx = 0; xx < 4; ++xx)
            for (int jj = 0; jj < 8; ++jj)
                acc[xx][jj] = bl[jg0 + jj];
        for (int ci = 0; ci < CIN; ++ci) {
            float4 xv = *reinterpret_cast<const float4*>(&xl[ci * FW + x0]);
            float4 v0 = *reinterpret_cast<const float4*>(&vl[ci * JP + jg0]);
            float4 v1 = *reinterpret_cast<const float4*>(&vl[ci * JP + jg0 + 4]);
            float xa[4] = {xv.x, xv.y, xv.z, xv.w};
            float va[8] = {v0.x, v0.y, v0.z, v0.w, v1.x, v1.y, v1.z, v1.w};
            for (int xx = 0; xx < 4; ++xx)
                for (int jj = 0; jj < 8; ++jj)
                    acc[xx][jj] = fmaf(xa[xx], va[jj], acc[xx][jj]);
        }
        __hip_bfloat16* mbase = Mb + ((size_t)y * FW) * JP;
        for (int xx = 0; xx < 4; ++xx) {
            uint32_t* row = (uint32_t*)(mbase + (size_t)(x0 + xx) * JP + jg0);
            uint4 pk;
            pk.x = pkbf(acc[xx][0], acc[xx][1]);
            pk.y = pkbf(acc[xx][2], acc[xx][3]);
            pk.z = pkbf(acc[xx][4], acc[xx][5]);
            pk.w = pkbf(acc[xx][6], acc[xx][7]);
            *reinterpret_cast<uint4*>(row) = pk;
        }
    }
}

// ---------------- k3: slab-prefetch + gather-sum over 45 y's + LDS epilogue ----------------
__global__ __launch_bounds__(256) void k3_gather(
    const __hip_bfloat16* __restrict__ M, const float* __restrict__ anchors,
    const float* __restrict__ cls_b, const float* __restrict__ reg_b,
    const int* __restrict__ off, float* __restrict__ out) {
    __shared__ int sidx[ANB * FH];       // 4.5 KB
    __shared__ float sanch[ANB * 77];    // 7.7 KB
    __shared__ float sout[ANB * 77];     // 7.7 KB
    __shared__ float sbias[JN];
    int tid = threadIdx.x;
    int wg = blockIdx.x;
    int b = (wg % 8) * 2 + ((wg >> 3) & 1);   // XCD x owns batches {2x,2x+1}
    int chunk = wg >> 4;
    int n0 = chunk * ANB;
    int nvalid = NANCH - n0; if (nvalid > ANB) nvalid = ANB;

    // --- issue linear L2-prefetch of this block's share of slab b (oldest in queue) ---
    const char* slab = (const char*)(M + (size_t)b * SB);
    int pbase = chunk * PFQ;
    float keep = 0.f;
    {
        int p0 = pbase + tid * 16;
        if (p0 + 16 <= SLAB_BYTES) {
            float4 v = *reinterpret_cast<const float4*>(slab + p0);
            keep += v.x + v.y + v.z + v.w;
        }
        int p1 = pbase + 4096 + tid * 16;
        if (tid < 80 && p1 + 16 <= SLAB_BYTES) {
            float4 v = *reinterpret_cast<const float4*>(slab + p1);
            keep += v.x + v.y + v.z + v.w;
        }
    }
    // --- stage indices, anchor rows, biases ---
    for (int i = tid; i < ANB * FH; i += 256) {
        int nl = i / FH;
        sidx[i] = (nl < nvalid) ? off[n0 * FH + i] : ZOFF;
    }
    for (int i = tid; i < nvalid * 77; i += 256)
        sanch[i] = anchors[(size_t)n0 * 77 + i];
    if (tid < JN) sbias[tid] = (tid < 2) ? cls_b[tid] : reg_b[tid - 2];
    __syncthreads();
    asm volatile("" :: "v"(keep));   // forces prefetch completion; not DCE'd

    int lb = tid / 10;
    int jg = tid % 10;
    if (lb < nvalid && tid < ANB * 10) {
        const __hip_bfloat16* mb = M + (size_t)b * SB + jg * 8;
        const int* si = sidx + lb * FH;
        float s[8];
        #pragma unroll
        for (int e = 0; e < 8; ++e) s[e] = 0.f;
        #pragma unroll
        for (int y = 0; y < FH; ++y) {
            int o = si[y];
            uint4 v = *reinterpret_cast<const uint4*>(mb + o);
            uint32_t u[4] = {v.x, v.y, v.z, v.w};
            #pragma unroll
            for (int p = 0; p < 4; ++p) {
                s[2 * p]     += __uint_as_float(u[p] << 16);
                s[2 * p + 1] += __uint_as_float(u[p] & 0xFFFF0000u);
            }
        }
        float* so = sout + lb * 77;
        const float* sa = sanch + lb * 77;
        int j0 = jg * 8;
        #pragma unroll
        for (int e = 0; e < 8; ++e) {
            int j = j0 + e;
            if (j < 2)       so[j]     = s[e] + sbias[j];
            else if (j < JN) so[j + 2] = s[e] + sbias[j] + sa[j + 2];
        }
        if (jg == 0) { so[2] = sa[2]; so[3] = sa[3]; }
    }
    __syncthreads();
    // --- coalesced linear write-out ---
    float* dsl = out + ((size_t)b * NANCH + n0) * 77;
    int tot = nvalid * 77;
    for (int i = tid; i < tot; i += 256) dsl[i] = sout[i];
}

extern "C" void kernel_launch(void* const* d_in, const int* in_sizes, int n_in,
                              void* d_out, int out_size, void* d_ws, size_t ws_size,
                              hipStream_t stream) {
    const float* x       = (const float*)d_in[0];
    const float* conv_w  = (const float*)d_in[1];
    const float* conv_b  = (const float*)d_in[2];
    const float* cls_w   = (const float*)d_in[3];
    const float* cls_b   = (const float*)d_in[4];
    const float* reg_w   = (const float*)d_in[5];
    const float* reg_b   = (const float*)d_in[6];
    const float* anchors = (const float*)d_in[7];
    const int* cut_xs    = (const int*)d_in[8];
    const uint8_t* invalid = (const uint8_t*)d_in[9];
    float* out = (float*)d_out;

    float* V     = (float*)d_ws;                          // FH*CIN*JP f32
    float* biasM = V + FH * CIN * JP;                     // FH*JP f32
    __hip_bfloat16* M = (__hip_bfloat16*)(biasM + FH * JP);   // BB*SB bf16 (16B-aligned)
    int*   off   = (int*)((char*)M + (size_t)BB * SB * sizeof(__hip_bfloat16));

    int n_off_blocks = (NANCH * FH + 255) / 256;          // 490
    k1_weights<<<90 + n_off_blocks, 256, 0, stream>>>(conv_w, conv_b, cls_w, reg_w,
                                                      cut_xs, invalid, V, biasM, off);
    k2_feat<<<BB * FH, 256, 0, stream>>>(x, V, biasM, M);
    k3_gather<<<16 * CPB, 256, 0, stream>>>(M, anchors, cls_b, reg_b, off, out);
}